// Round 18
// baseline (209.384 us; speedup 1.0000x reference)
//
#include <hip/hip_runtime.h>
#include <cstdint>
#include <cstddef>

typedef unsigned short u16;
typedef unsigned int u32;
typedef __attribute__((ext_vector_type(2))) float f32x2;
typedef __attribute__((ext_vector_type(4))) float f32x4;
typedef __attribute__((ext_vector_type(8))) short short8;
typedef __attribute__((ext_vector_type(2))) u32 u32x2;
typedef __attribute__((ext_vector_type(4))) u32 u32x4;

#define DEV static __device__ __forceinline__
#define HW 16384

DEV u16 f2bf(float f) {
  u32 u = __float_as_uint(f);
  u = (u + 0x7fffu + ((u >> 16) & 1u)) >> 16;
  return (u16)u;
}
DEV float bf2f(u16 h) { return __uint_as_float(((u32)h) << 16); }

DEV u32 packsplit(float f) {
  u16 h = f2bf(f);
  u16 l = f2bf(f - bf2f(h));
  return (u32)h | ((u32)l << 16);
}
DEV void unpack8(const u32* w, short8& hi, short8& lo) {
  #pragma unroll
  for (int i = 0; i < 8; ++i) {
    hi[i] = (short)(u16)w[i];
    lo[i] = (short)(u16)(w[i] >> 16);
  }
}
DEV void mfma3(f32x4& acc, short8 ah, short8 al, short8 bh, short8 bl) {
  acc = __builtin_amdgcn_mfma_f32_16x16x32_bf16(ah, bh, acc, 0, 0, 0);
  acc = __builtin_amdgcn_mfma_f32_16x16x32_bf16(ah, bl, acc, 0, 0, 0);
  acc = __builtin_amdgcn_mfma_f32_16x16x32_bf16(al, bh, acc, 0, 0, 0);
}

// ---------------------------------------------------------------------------
// ksplit: f32 -> packed split-bf16 u32 (hi | lo<<16)
// ---------------------------------------------------------------------------
__global__ __launch_bounds__(256) void ksplit(const float* __restrict__ in,
                                              u32* __restrict__ out, int n) {
  int i = blockIdx.x * 256 + threadIdx.x;
  if (i < n) out[i] = packsplit(in[i]);
}

// ---------------------------------------------------------------------------
// gemm13: C = A * B, K=192, BM=192, BN=NFRAG*64, 8 waves (2m x 4n),
// 6 K-phases. Round-10 measured-best structure, tile width templated:
// A packed u32 global -> hi/lo u16 LDS planes, stride 32 + slot-XOR swizzle;
// B staged packed u32 stride 34, spread-row stores (conflicts = 0);
// 2 barriers/phase. NFRAG=2 for the high-block-count qkv gemm; NFRAG=1 for
// the final gemm (2x blocks -> 4 blocks/CU, hides per-phase barrier drains).
// blockIdx.y selects A-row-block (m0=y*192), B source (y==0 ? B0 : B1) and
// C target (y==0 -> C0 stride 192, else C1 stride 384 at rows (y-1)*192).
// ---------------------------------------------------------------------------
template<int ABATCH, int BPACKED, int NFRAG>
__global__ __launch_bounds__(512, 4) void gemm13(const u32* __restrict__ Asp,
                                                 const u32* __restrict__ B0,
                                                 const u32* __restrict__ B1,
                                                 float* __restrict__ C0,
                                                 float* __restrict__ C1) {
  __shared__ u16 Ah[192 * 32];            // 12288 B
  __shared__ u16 Al[192 * 32];            // 12288 B
  __shared__ u32 Bs[NFRAG * 64 * 34];     // 8704*NFRAG B
  const int t = threadIdx.x, lane = t & 63, wid = t >> 6;
  const int b = blockIdx.z, n0 = blockIdx.x * (NFRAG * 64), y = blockIdx.y;
  const int m0 = y * 192;
  const u32* Ab = Asp + (ABATCH ? (size_t)b * 192 * 192 : 0) + (size_t)m0 * 192;
  const u32* Bb = (y == 0 ? B0 : B1) + (size_t)b * 192 * (size_t)HW;
  float* Cb = (y == 0) ? (C0 + (size_t)b * 192 * (size_t)HW)
                       : (C1 + ((size_t)b * 384 + (size_t)(y - 1) * 192) * (size_t)HW);
  const int wr = wid >> 2, wc = wid & 3;
  const int g = lane >> 4, r16 = lane & 15;
  const int bk = t >> 4;       // k-col 0..31
  const int bn = t & 15;       // base n; rows bn+16j, j<4*NFRAG
  f32x4 acc[6][NFRAG] = {};

  int adst[3];
  int asrc_row[3], asrc_kc[3];
  #pragma unroll
  for (int i = 0; i < 3; ++i) {
    int vi = t + i * 512;
    int row = vi >> 3, kv = (vi & 7) << 2;
    asrc_row[i] = row; asrc_kc[i] = kv;
    adst[i] = row * 32 + (((kv >> 3) ^ ((row >> 1) & 3)) << 3) + (kv & 7);
  }
  const int aswz = (g ^ ((r16 >> 1) & 3)) << 3;

  u32 Breg[4 * NFRAG], Bnext[4 * NFRAG];
  u32x4 Areg[3];
  #pragma unroll
  for (int j = 0; j < 4 * NFRAG; ++j)
    Breg[j] = Bb[(size_t)bk * HW + n0 + bn + 16 * j];
  #pragma unroll
  for (int i = 0; i < 3; ++i)
    Areg[i] = *(const u32x4*)&Ab[(size_t)asrc_row[i] * 192 + asrc_kc[i]];
  #pragma unroll 1
  for (int p = 0; p < 6; ++p) {
    #pragma unroll
    for (int j = 0; j < 4 * NFRAG; ++j)
      Bs[(bn + 16 * j) * 34 + bk] =
          BPACKED ? Breg[j] : packsplit(__uint_as_float(Breg[j]));
    #pragma unroll
    for (int i = 0; i < 3; ++i) {
      u32 h01 = (Areg[i][0] & 0xffffu) | (Areg[i][1] << 16);
      u32 h23 = (Areg[i][2] & 0xffffu) | (Areg[i][3] << 16);
      u32 l01 = (Areg[i][0] >> 16) | (Areg[i][1] & 0xffff0000u);
      u32 l23 = (Areg[i][2] >> 16) | (Areg[i][3] & 0xffff0000u);
      u32x2 hq = {h01, h23}, lq = {l01, l23};
      *(u32x2*)&Ah[adst[i]] = hq;
      *(u32x2*)&Al[adst[i]] = lq;
    }
    if (p < 5) {
      #pragma unroll
      for (int j = 0; j < 4 * NFRAG; ++j)
        Bnext[j] = Bb[(size_t)((p + 1) * 32 + bk) * HW + n0 + bn + 16 * j];
    }
    __syncthreads();
    if (p < 5) {
      #pragma unroll
      for (int i = 0; i < 3; ++i)
        Areg[i] = *(const u32x4*)&Ab[(size_t)asrc_row[i] * 192 + (p + 1) * 32 + asrc_kc[i]];
    }
    short8 bh[NFRAG], bl[NFRAG];
    #pragma unroll
    for (int nf = 0; nf < NFRAG; ++nf) {
      u32 bw[8];
      const u32* bp = &Bs[(wc * 16 * NFRAG + nf * 16 + r16) * 34 + g * 8];
      *(u32x2*)&bw[0] = *(const u32x2*)&bp[0];
      *(u32x2*)&bw[2] = *(const u32x2*)&bp[2];
      *(u32x2*)&bw[4] = *(const u32x2*)&bp[4];
      *(u32x2*)&bw[6] = *(const u32x2*)&bp[6];
      unpack8(bw, bh[nf], bl[nf]);
    }
    #pragma unroll
    for (int mf = 0; mf < 6; ++mf) {
      const int ar = (wr * 96 + mf * 16 + r16) * 32 + aswz;
      short8 ah = *(const short8*)&Ah[ar];
      short8 al = *(const short8*)&Al[ar];
      #pragma unroll
      for (int nf = 0; nf < NFRAG; ++nf) {
        acc[mf][nf] = __builtin_amdgcn_mfma_f32_16x16x32_bf16(ah, bh[nf], acc[mf][nf], 0, 0, 0);
        acc[mf][nf] = __builtin_amdgcn_mfma_f32_16x16x32_bf16(ah, bl[nf], acc[mf][nf], 0, 0, 0);
        acc[mf][nf] = __builtin_amdgcn_mfma_f32_16x16x32_bf16(al, bh[nf], acc[mf][nf], 0, 0, 0);
      }
    }
    __syncthreads();
    #pragma unroll
    for (int j = 0; j < 4 * NFRAG; ++j) Breg[j] = Bnext[j];
  }
  #pragma unroll
  for (int mf = 0; mf < 6; ++mf)
    #pragma unroll
    for (int nf = 0; nf < NFRAG; ++nf)
      #pragma unroll
      for (int rr = 0; rr < 4; ++rr)
        Cb[(size_t)(wr * 96 + mf * 16 + g * 4 + rr) * HW + n0 +
           wc * 16 * NFRAG + nf * 16 + r16] = acc[mf][nf][rr];
}

// ---------------------------------------------------------------------------
// K2: depthwise 3x3 (pad 1), f32 in (batch stride cstIn*HW), PACKED u32 out
// (batch stride 192*HW).
// ---------------------------------------------------------------------------
template<int SSQ>
__global__ __launch_bounds__(512) void k2_dw(const float* __restrict__ Tin, int cstIn,
                                             const float* __restrict__ wdw, int wco,
                                             u32* __restrict__ O,
                                             float* __restrict__ ssq, int sspath) {
  const int rt = blockIdx.x, cg = blockIdx.y, b = blockIdx.z;
  const int t = threadIdx.x, lane = t & 63, w = t >> 6;
  __shared__ float In[8][10][132];
  for (int idx = t; idx < 10400; idx += 512) {
    int ch = idx / 1300, rem = idx % 1300;
    int r = rem / 130, ci = rem % 130;
    int gr = rt * 8 + r - 1, gc = ci - 1;
    float v = 0.f;
    if (gr >= 0 && gr < 128 && gc >= 0 && gc < 128)
      v = Tin[((size_t)b * cstIn + cg * 8 + ch) * HW + gr * 128 + gc];
    In[ch][r][ci] = v;
  }
  float wv[9];
  #pragma unroll
  for (int j = 0; j < 9; ++j) wv[j] = wdw[(size_t)(wco + cg * 8 + w) * 9 + j];
  __syncthreads();
  float s = 0.f;
  u32* Op = O + ((size_t)b * 192 + cg * 8 + w) * HW + rt * 8 * 128 + 2 * lane;
  #pragma unroll
  for (int i = 0; i < 8; ++i) {
    float a0 = 0.f, a1 = 0.f;
    #pragma unroll
    for (int dr = 0; dr < 3; ++dr) {
      f32x2 u0 = *(const f32x2*)&In[w][i + dr][2 * lane];
      f32x2 u1 = *(const f32x2*)&In[w][i + dr][2 * lane + 2];
      a0 += wv[dr * 3] * u0[0] + wv[dr * 3 + 1] * u0[1] + wv[dr * 3 + 2] * u1[0];
      a1 += wv[dr * 3] * u0[1] + wv[dr * 3 + 1] * u1[0] + wv[dr * 3 + 2] * u1[1];
    }
    u32x2 o = {packsplit(a0), packsplit(a1)};
    *(u32x2*)&Op[(size_t)i * 128] = o;
    if (SSQ) s += a0 * a0 + a1 * a1;
  }
  if (SSQ) {
    #pragma unroll
    for (int off = 32; off; off >>= 1) s += __shfl_down(s, off);
    if (lane == 0) ssq[(((size_t)b * 2 + sspath) * 192 + cg * 8 + w) * 16 + rt] = s;
  }
}

// ---------------------------------------------------------------------------
// K3: Gram partials gp[bh][16][1024] from PACKED q/k.
// ---------------------------------------------------------------------------
__global__ __launch_bounds__(256) void k3_gram(const u32* __restrict__ q,
                                               const u32* __restrict__ k,
                                               float* __restrict__ gp) {
  const int ck = blockIdx.x, bh = blockIdx.y;  // 16, 24
  const int b = bh / 6, h = bh % 6;
  const int t = threadIdx.x, lane = t & 63, wid = t >> 6;
  const int r16 = lane & 15, g = lane >> 4;
  const int chunk = ck * 4 + wid;  // 0..63
  const size_t rbase = ((size_t)b * 192 + h * 32 + r16) * HW;
  const u32* qp = q + rbase;
  const u32* kp = k + rbase;
  __shared__ float red[4][1024];
  f32x4 acc[2][2] = {};
  #pragma unroll 1
  for (int s = 0; s < 8; ++s) {
    int n = chunk * 256 + s * 32 + g * 8;
    u32 wq0[8], wq1[8], wk0[8], wk1[8];
    *(u32x4*)&wq0[0] = *(const u32x4*)&qp[n];
    *(u32x4*)&wq0[4] = *(const u32x4*)&qp[n + 4];
    *(u32x4*)&wq1[0] = *(const u32x4*)&qp[(size_t)16 * HW + n];
    *(u32x4*)&wq1[4] = *(const u32x4*)&qp[(size_t)16 * HW + n + 4];
    *(u32x4*)&wk0[0] = *(const u32x4*)&kp[n];
    *(u32x4*)&wk0[4] = *(const u32x4*)&kp[n + 4];
    *(u32x4*)&wk1[0] = *(const u32x4*)&kp[(size_t)16 * HW + n];
    *(u32x4*)&wk1[4] = *(const u32x4*)&kp[(size_t)16 * HW + n + 4];
    short8 a0h, a0l, a1h, a1l, b0h, b0l, b1h, b1l;
    unpack8(wq0, a0h, a0l);
    unpack8(wq1, a1h, a1l);
    unpack8(wk0, b0h, b0l);
    unpack8(wk1, b1h, b1l);
    mfma3(acc[0][0], a0h, a0l, b0h, b0l);
    mfma3(acc[0][1], a0h, a0l, b1h, b1l);
    mfma3(acc[1][0], a1h, a1l, b0h, b0l);
    mfma3(acc[1][1], a1h, a1l, b1h, b1l);
  }
  #pragma unroll
  for (int mf = 0; mf < 2; ++mf)
    #pragma unroll
    for (int nf = 0; nf < 2; ++nf)
      #pragma unroll
      for (int rr = 0; rr < 4; ++rr)
        red[wid][(mf * 16 + g * 4 + rr) * 32 + nf * 16 + r16] = acc[mf][nf][rr];
  __syncthreads();
  float* outp = gp + ((size_t)bh * 16 + ck) * 1024;
  #pragma unroll
  for (int e = t; e < 1024; e += 256)
    outp[e] = red[0][e] + red[1][e] + red[2][e] + red[3][e];
}

// ---------------------------------------------------------------------------
// K4: reduce partials, normalize, temperature, 4x topk-softmax, combine,
// fold W_proj (LDS-cached) -> mcp packed u32. 512 threads.
// ---------------------------------------------------------------------------
__global__ __launch_bounds__(512) void k4_comb(const float* __restrict__ gp,
                                               const float* __restrict__ ssq,
                                               const float* __restrict__ temp,
                                               const float* __restrict__ aw,
                                               const float* __restrict__ wproj,
                                               u32* __restrict__ mcp) {
  const int bh = blockIdx.x, b = bh / 6, h = bh % 6;
  const int t = threadIdx.x;
  __shared__ float Gs[1024];
  __shared__ float Acm[1024];
  __shared__ float Wp[192 * 32];
  __shared__ float nq[32], nk[32];
  #pragma unroll
  for (int i = 0; i < 3; ++i) {
    int idx = t + i * 512;
    int row = idx >> 3, c4 = (idx & 7) << 2;
    *(f32x4*)&Wp[row * 32 + c4] = *(const f32x4*)&wproj[(size_t)row * 192 + h * 32 + c4];
  }
  {
    const float* p = gp + (size_t)bh * 16 * 1024 + 2 * t;
    f32x2 s = {};
    #pragma unroll
    for (int ch = 0; ch < 16; ++ch) {
      f32x2 v = *(const f32x2*)&p[(size_t)ch * 1024];
      s[0] += v[0]; s[1] += v[1];
    }
    *(f32x2*)&Gs[2 * t] = s;
  }
  if (t < 64) {
    int c = t & 31, pk = t >> 5;
    const float* sp = ssq + (((size_t)b * 2 + pk) * 192 + h * 32 + c) * 16;
    f32x4 s4 = {};
    #pragma unroll
    for (int i = 0; i < 4; ++i) {
      f32x4 v = *(const f32x4*)&sp[4 * i];
      s4[0] += v[0]; s4[1] += v[1]; s4[2] += v[2]; s4[3] += v[3];
    }
    float nr = fmaxf(sqrtf(s4[0] + s4[1] + s4[2] + s4[3]), 1e-12f);
    if (pk == 0) nq[c] = nr; else nk[c] = nr;
  }
  __syncthreads();
  const float T = temp[h];
  {
    int c = (2 * t) >> 5;
    f32x2 v = *(const f32x2*)&Gs[2 * t];
    float inq = T / nq[c];
    v[0] = v[0] * inq / nk[(2 * t) & 31];
    v[1] = v[1] * inq / nk[(2 * t + 1) & 31];
    __syncthreads();
    *(f32x2*)&Gs[2 * t] = v;
  }
  __syncthreads();
  const float aw0 = aw[0], aw1 = aw[1], aw2 = aw[2], aw3 = aw[3];
  const int half = t >> 5, d = t & 31;
  #pragma unroll
  for (int it = 0; it < 2; ++it) {
    const int c = it * 16 + half;
    const float v = Gs[c * 32 + d];
    int cnt = 0;
    #pragma unroll
    for (int dd = 0; dd < 32; ++dd) cnt += (Gs[c * 32 + dd] >= v) ? 1 : 0;
    float c0 = v;
    float c1 = (cnt >= 16) ? v : -3.0e38f;
    float c2 = (cnt >= 21) ? v : -3.0e38f;
    float c3 = (cnt >= 24) ? v : -3.0e38f;
    float c4 = (cnt >= 25) ? v : -3.0e38f;
    #pragma unroll
    for (int off = 16; off; off >>= 1) {
      c0 = fmaxf(c0, __shfl_xor(c0, off));
      c1 = fmaxf(c1, __shfl_xor(c1, off));
      c2 = fmaxf(c2, __shfl_xor(c2, off));
      c3 = fmaxf(c3, __shfl_xor(c3, off));
      c4 = fmaxf(c4, __shfl_xor(c4, off));
    }
    const float m = c0;
    const float ex = expf(v - m);
    float z1 = (v >= c1) ? ex : 0.f;
    float z2 = (v >= c2) ? ex : 0.f;
    float z3 = (v >= c3) ? ex : 0.f;
    float z4 = (v >= c4) ? ex : 0.f;
    #pragma unroll
    for (int off = 16; off; off >>= 1) {
      z1 += __shfl_xor(z1, off);
      z2 += __shfl_xor(z2, off);
      z3 += __shfl_xor(z3, off);
      z4 += __shfl_xor(z4, off);
    }
    float a = 0.f;
    a += (v >= c1) ? aw0 * ex / z1 : 0.f;
    a += (v >= c2) ? aw1 * ex / z2 : 0.f;
    a += (v >= c3) ? aw2 * ex / z3 : 0.f;
    a += (v >= c4) ? aw3 * ex / z4 : 0.f;
    Acm[c * 32 + d] = a;
  }
  __syncthreads();
  #pragma unroll
  for (int i = 0; i < 12; ++i) {
    int idx = t + i * 512;
    int co = idx >> 5, dd = idx & 31;
    float s = 0.f;
    #pragma unroll
    for (int c = 0; c < 32; ++c) s += Wp[co * 32 + c] * Acm[c * 32 + dd];
    mcp[((size_t)b * 192 + co) * 192 + h * 32 + dd] = packsplit(s);
  }
}

// ---------------------------------------------------------------------------
extern "C" void kernel_launch(void* const* d_in, const int* in_sizes, int n_in,
                              void* d_out, int out_size, void* d_ws, size_t ws_size,
                              hipStream_t stream) {
  const float* x     = (const float*)d_in[0];
  const float* ref   = (const float*)d_in[1];
  const float* wqkv  = (const float*)d_in[2];
  const float* wdw   = (const float*)d_in[3];
  const float* wproj = (const float*)d_in[4];
  const float* temp  = (const float*)d_in[5];
  const float* aw    = (const float*)d_in[6];
  float* out = (float*)d_out;
  char* ws = (char*)d_ws;

  const size_t S = (size_t)4 * 192 * HW * 4;  // 50331648 bytes
  float* Ckv = (float*)(ws);                  // k+v conv-out (2S) [b][384][HW]
  float* Cq  = (float*)(ws + 2 * S);          // q conv-out (S)    [b][192][HW]
  u32*   qpk = (u32*)(ws + 3 * S);            // packed q (S); later vpk
  float* gp  = (float*)(ws + 4 * S);                        // 1572864 B
  float* ssq = (float*)(ws + 4 * S + 1572864);              // 98304 B
  u32*   wsp = (u32*)(ws + 4 * S + 1572864 + 98304);        // 442368 B
  u32*   mcp = (u32*)(ws + 4 * S + 1572864 + 98304 + 442368); // 589824 B
  u32*   kpk = (u32*)Cq;    // alias: Cq dead after k2(q)
  u32*   vpk = qpk;         // alias: qpk dead after k3

  // pre-split w_qkv (576x192)
  ksplit<<<dim3(432), 256, 0, stream>>>(wqkv, wsp, 576 * 192);
  // merged q+k+v conv1x1: y=0 -> q from x into Cq; y=1,2 -> k,v from ref into Ckv
  gemm13<0, 0, 2><<<dim3(128, 3, 4), 512, 0, stream>>>(wsp, (const u32*)x,
                                                       (const u32*)ref, Cq, Ckv);
  // q dwconv -> qpk + ssq0
  k2_dw<1><<<dim3(16, 24, 4), 512, 0, stream>>>(Cq, 192, wdw, 0, qpk, ssq, 0);
  // k dwconv (Ckv rows 0..191) -> kpk (= Cq slot, dead) + ssq1
  k2_dw<1><<<dim3(16, 24, 4), 512, 0, stream>>>(Ckv, 384, wdw, 192, kpk, ssq, 1);
  // Gram partials
  k3_gram<<<dim3(16, 24), 256, 0, stream>>>(qpk, kpk, gp);
  // v dwconv (Ckv rows 192..383) -> vpk (= qpk slot, dead after k3)
  k2_dw<0><<<dim3(16, 24, 4), 512, 0, stream>>>(Ckv + (size_t)192 * HW, 384, wdw, 384,
                                                vpk, nullptr, 2);
  // combine + fold proj (writes packed mc)
  k4_comb<<<dim3(24), 512, 0, stream>>>(gp, ssq, temp, aw, wproj, mcp);
  // final batched GEMM at BN=64 (1024 blocks -> 4 blocks/CU, latency-hiding)
  gemm13<1, 1, 1><<<dim3(256, 1, 4), 512, 0, stream>>>(mcp, vpk, vpk, out, out);
}

// Round 19
// 207.630 us; speedup vs baseline: 1.0085x; 1.0085x over previous
//
#include <hip/hip_runtime.h>
#include <cstdint>
#include <cstddef>

typedef unsigned short u16;
typedef unsigned int u32;
typedef __attribute__((ext_vector_type(2))) float f32x2;
typedef __attribute__((ext_vector_type(4))) float f32x4;
typedef __attribute__((ext_vector_type(8))) short short8;
typedef __attribute__((ext_vector_type(2))) u32 u32x2;
typedef __attribute__((ext_vector_type(4))) u32 u32x4;

#define DEV static __device__ __forceinline__
#define HW 16384

DEV u16 f2bf(float f) {
  u32 u = __float_as_uint(f);
  u = (u + 0x7fffu + ((u >> 16) & 1u)) >> 16;
  return (u16)u;
}
DEV float bf2f(u16 h) { return __uint_as_float(((u32)h) << 16); }

DEV u32 packsplit(float f) {
  u16 h = f2bf(f);
  u16 l = f2bf(f - bf2f(h));
  return (u32)h | ((u32)l << 16);
}
DEV void unpack8(const u32* w, short8& hi, short8& lo) {
  #pragma unroll
  for (int i = 0; i < 8; ++i) {
    hi[i] = (short)(u16)w[i];
    lo[i] = (short)(u16)(w[i] >> 16);
  }
}
DEV void mfma3(f32x4& acc, short8 ah, short8 al, short8 bh, short8 bl) {
  acc = __builtin_amdgcn_mfma_f32_16x16x32_bf16(ah, bh, acc, 0, 0, 0);
  acc = __builtin_amdgcn_mfma_f32_16x16x32_bf16(ah, bl, acc, 0, 0, 0);
  acc = __builtin_amdgcn_mfma_f32_16x16x32_bf16(al, bh, acc, 0, 0, 0);
}

// ---------------------------------------------------------------------------
// ksplit: f32 -> packed split-bf16 u32 (hi | lo<<16)
// ---------------------------------------------------------------------------
__global__ __launch_bounds__(256) void ksplit(const float* __restrict__ in,
                                              u32* __restrict__ out, int n) {
  int i = blockIdx.x * 256 + threadIdx.x;
  if (i < n) out[i] = packsplit(in[i]);
}

// ---------------------------------------------------------------------------
// gemm6: C = A * B, K=192, BM=192, BN=128, 8 waves (2m x 4n), 6 K-phases.
// Session-best structure (measured 208.2 us total): A packed u32 global ->
// hi/lo u16 LDS planes, stride 32 + slot-XOR swizzle; B staged packed u32
// stride 34, spread-row stores (bank conflicts = 0); 2 barriers/phase.
// blockIdx.y selects A-row-block (m0=y*192), B source (y==0 ? B0 : B1) and
// C target (y==0 -> C0 stride 192, else C1 stride 384 at rows (y-1)*192).
// ---------------------------------------------------------------------------
template<int ABATCH, int BPACKED>
__global__ __launch_bounds__(512, 4) void gemm6(const u32* __restrict__ Asp,
                                                const u32* __restrict__ B0,
                                                const u32* __restrict__ B1,
                                                float* __restrict__ C0,
                                                float* __restrict__ C1) {
  __shared__ u16 Ah[192 * 32];  // 12288 B
  __shared__ u16 Al[192 * 32];  // 12288 B
  __shared__ u32 Bs[128 * 34];  // 17408 B
  const int t = threadIdx.x, lane = t & 63, wid = t >> 6;
  const int b = blockIdx.z, n0 = blockIdx.x * 128, y = blockIdx.y;
  const int m0 = y * 192;
  const u32* Ab = Asp + (ABATCH ? (size_t)b * 192 * 192 : 0) + (size_t)m0 * 192;
  const u32* Bb = (y == 0 ? B0 : B1) + (size_t)b * 192 * (size_t)HW;
  float* Cb = (y == 0) ? (C0 + (size_t)b * 192 * (size_t)HW)
                       : (C1 + ((size_t)b * 384 + (size_t)(y - 1) * 192) * (size_t)HW);
  const int wr = wid >> 2, wc = wid & 3;
  const int g = lane >> 4, r16 = lane & 15;
  const int bk = t >> 4;       // k-col 0..31
  const int bn = t & 15;       // base n; rows bn+16j, j=0..7
  f32x4 acc[6][2] = {};

  int adst[3];
  int asrc_row[3], asrc_kc[3];
  #pragma unroll
  for (int i = 0; i < 3; ++i) {
    int vi = t + i * 512;
    int row = vi >> 3, kv = (vi & 7) << 2;
    asrc_row[i] = row; asrc_kc[i] = kv;
    adst[i] = row * 32 + (((kv >> 3) ^ ((row >> 1) & 3)) << 3) + (kv & 7);
  }
  const int aswz = (g ^ ((r16 >> 1) & 3)) << 3;

  u32 Breg[8], Bnext[8];
  u32x4 Areg[3];
  #pragma unroll
  for (int j = 0; j < 8; ++j)
    Breg[j] = Bb[(size_t)bk * HW + n0 + bn + 16 * j];
  #pragma unroll
  for (int i = 0; i < 3; ++i)
    Areg[i] = *(const u32x4*)&Ab[(size_t)asrc_row[i] * 192 + asrc_kc[i]];
  #pragma unroll 1
  for (int p = 0; p < 6; ++p) {
    #pragma unroll
    for (int j = 0; j < 8; ++j)
      Bs[(bn + 16 * j) * 34 + bk] =
          BPACKED ? Breg[j] : packsplit(__uint_as_float(Breg[j]));
    #pragma unroll
    for (int i = 0; i < 3; ++i) {
      u32 h01 = (Areg[i][0] & 0xffffu) | (Areg[i][1] << 16);
      u32 h23 = (Areg[i][2] & 0xffffu) | (Areg[i][3] << 16);
      u32 l01 = (Areg[i][0] >> 16) | (Areg[i][1] & 0xffff0000u);
      u32 l23 = (Areg[i][2] >> 16) | (Areg[i][3] & 0xffff0000u);
      u32x2 hq = {h01, h23}, lq = {l01, l23};
      *(u32x2*)&Ah[adst[i]] = hq;
      *(u32x2*)&Al[adst[i]] = lq;
    }
    if (p < 5) {
      #pragma unroll
      for (int j = 0; j < 8; ++j)
        Bnext[j] = Bb[(size_t)((p + 1) * 32 + bk) * HW + n0 + bn + 16 * j];
    }
    __syncthreads();
    if (p < 5) {
      #pragma unroll
      for (int i = 0; i < 3; ++i)
        Areg[i] = *(const u32x4*)&Ab[(size_t)asrc_row[i] * 192 + (p + 1) * 32 + asrc_kc[i]];
    }
    short8 bh[2], bl[2];
    #pragma unroll
    for (int nf = 0; nf < 2; ++nf) {
      u32 bw[8];
      const u32* bp = &Bs[(wc * 32 + nf * 16 + r16) * 34 + g * 8];
      *(u32x2*)&bw[0] = *(const u32x2*)&bp[0];
      *(u32x2*)&bw[2] = *(const u32x2*)&bp[2];
      *(u32x2*)&bw[4] = *(const u32x2*)&bp[4];
      *(u32x2*)&bw[6] = *(const u32x2*)&bp[6];
      unpack8(bw, bh[nf], bl[nf]);
    }
    #pragma unroll
    for (int mf = 0; mf < 6; ++mf) {
      const int ar = (wr * 96 + mf * 16 + r16) * 32 + aswz;
      short8 ah = *(const short8*)&Ah[ar];
      short8 al = *(const short8*)&Al[ar];
      #pragma unroll
      for (int nf = 0; nf < 2; ++nf) {
        acc[mf][nf] = __builtin_amdgcn_mfma_f32_16x16x32_bf16(ah, bh[nf], acc[mf][nf], 0, 0, 0);
        acc[mf][nf] = __builtin_amdgcn_mfma_f32_16x16x32_bf16(ah, bl[nf], acc[mf][nf], 0, 0, 0);
        acc[mf][nf] = __builtin_amdgcn_mfma_f32_16x16x32_bf16(al, bh[nf], acc[mf][nf], 0, 0, 0);
      }
    }
    __syncthreads();
    #pragma unroll
    for (int j = 0; j < 8; ++j) Breg[j] = Bnext[j];
  }
  #pragma unroll
  for (int mf = 0; mf < 6; ++mf)
    #pragma unroll
    for (int nf = 0; nf < 2; ++nf)
      #pragma unroll
      for (int rr = 0; rr < 4; ++rr)
        Cb[(size_t)(wr * 96 + mf * 16 + g * 4 + rr) * HW + n0 + wc * 32 + nf * 16 + r16] =
            acc[mf][nf][rr];
}

// ---------------------------------------------------------------------------
// K2: depthwise 3x3 (pad 1), f32 in (batch stride cstIn*HW), PACKED u32 out
// (batch stride 192*HW).
// ---------------------------------------------------------------------------
template<int SSQ>
__global__ __launch_bounds__(512) void k2_dw(const float* __restrict__ Tin, int cstIn,
                                             const float* __restrict__ wdw, int wco,
                                             u32* __restrict__ O,
                                             float* __restrict__ ssq, int sspath) {
  const int rt = blockIdx.x, cg = blockIdx.y, b = blockIdx.z;
  const int t = threadIdx.x, lane = t & 63, w = t >> 6;
  __shared__ float In[8][10][132];
  for (int idx = t; idx < 10400; idx += 512) {
    int ch = idx / 1300, rem = idx % 1300;
    int r = rem / 130, ci = rem % 130;
    int gr = rt * 8 + r - 1, gc = ci - 1;
    float v = 0.f;
    if (gr >= 0 && gr < 128 && gc >= 0 && gc < 128)
      v = Tin[((size_t)b * cstIn + cg * 8 + ch) * HW + gr * 128 + gc];
    In[ch][r][ci] = v;
  }
  float wv[9];
  #pragma unroll
  for (int j = 0; j < 9; ++j) wv[j] = wdw[(size_t)(wco + cg * 8 + w) * 9 + j];
  __syncthreads();
  float s = 0.f;
  u32* Op = O + ((size_t)b * 192 + cg * 8 + w) * HW + rt * 8 * 128 + 2 * lane;
  #pragma unroll
  for (int i = 0; i < 8; ++i) {
    float a0 = 0.f, a1 = 0.f;
    #pragma unroll
    for (int dr = 0; dr < 3; ++dr) {
      f32x2 u0 = *(const f32x2*)&In[w][i + dr][2 * lane];
      f32x2 u1 = *(const f32x2*)&In[w][i + dr][2 * lane + 2];
      a0 += wv[dr * 3] * u0[0] + wv[dr * 3 + 1] * u0[1] + wv[dr * 3 + 2] * u1[0];
      a1 += wv[dr * 3] * u0[1] + wv[dr * 3 + 1] * u1[0] + wv[dr * 3 + 2] * u1[1];
    }
    u32x2 o = {packsplit(a0), packsplit(a1)};
    *(u32x2*)&Op[(size_t)i * 128] = o;
    if (SSQ) s += a0 * a0 + a1 * a1;
  }
  if (SSQ) {
    #pragma unroll
    for (int off = 32; off; off >>= 1) s += __shfl_down(s, off);
    if (lane == 0) ssq[(((size_t)b * 2 + sspath) * 192 + cg * 8 + w) * 16 + rt] = s;
  }
}

// ---------------------------------------------------------------------------
// K3: Gram partials gp[bh][16][1024] from PACKED q/k.
// ---------------------------------------------------------------------------
__global__ __launch_bounds__(256) void k3_gram(const u32* __restrict__ q,
                                               const u32* __restrict__ k,
                                               float* __restrict__ gp) {
  const int ck = blockIdx.x, bh = blockIdx.y;  // 16, 24
  const int b = bh / 6, h = bh % 6;
  const int t = threadIdx.x, lane = t & 63, wid = t >> 6;
  const int r16 = lane & 15, g = lane >> 4;
  const int chunk = ck * 4 + wid;  // 0..63
  const size_t rbase = ((size_t)b * 192 + h * 32 + r16) * HW;
  const u32* qp = q + rbase;
  const u32* kp = k + rbase;
  __shared__ float red[4][1024];
  f32x4 acc[2][2] = {};
  #pragma unroll 1
  for (int s = 0; s < 8; ++s) {
    int n = chunk * 256 + s * 32 + g * 8;
    u32 wq0[8], wq1[8], wk0[8], wk1[8];
    *(u32x4*)&wq0[0] = *(const u32x4*)&qp[n];
    *(u32x4*)&wq0[4] = *(const u32x4*)&qp[n + 4];
    *(u32x4*)&wq1[0] = *(const u32x4*)&qp[(size_t)16 * HW + n];
    *(u32x4*)&wq1[4] = *(const u32x4*)&qp[(size_t)16 * HW + n + 4];
    *(u32x4*)&wk0[0] = *(const u32x4*)&kp[n];
    *(u32x4*)&wk0[4] = *(const u32x4*)&kp[n + 4];
    *(u32x4*)&wk1[0] = *(const u32x4*)&kp[(size_t)16 * HW + n];
    *(u32x4*)&wk1[4] = *(const u32x4*)&kp[(size_t)16 * HW + n + 4];
    short8 a0h, a0l, a1h, a1l, b0h, b0l, b1h, b1l;
    unpack8(wq0, a0h, a0l);
    unpack8(wq1, a1h, a1l);
    unpack8(wk0, b0h, b0l);
    unpack8(wk1, b1h, b1l);
    mfma3(acc[0][0], a0h, a0l, b0h, b0l);
    mfma3(acc[0][1], a0h, a0l, b1h, b1l);
    mfma3(acc[1][0], a1h, a1l, b0h, b0l);
    mfma3(acc[1][1], a1h, a1l, b1h, b1l);
  }
  #pragma unroll
  for (int mf = 0; mf < 2; ++mf)
    #pragma unroll
    for (int nf = 0; nf < 2; ++nf)
      #pragma unroll
      for (int rr = 0; rr < 4; ++rr)
        red[wid][(mf * 16 + g * 4 + rr) * 32 + nf * 16 + r16] = acc[mf][nf][rr];
  __syncthreads();
  float* outp = gp + ((size_t)bh * 16 + ck) * 1024;
  #pragma unroll
  for (int e = t; e < 1024; e += 256)
    outp[e] = red[0][e] + red[1][e] + red[2][e] + red[3][e];
}

// ---------------------------------------------------------------------------
// K4: reduce partials, normalize, temperature, 4x topk-softmax, combine,
// fold W_proj (LDS-cached) -> mcp packed u32. 512 threads.
// ---------------------------------------------------------------------------
__global__ __launch_bounds__(512) void k4_comb(const float* __restrict__ gp,
                                               const float* __restrict__ ssq,
                                               const float* __restrict__ temp,
                                               const float* __restrict__ aw,
                                               const float* __restrict__ wproj,
                                               u32* __restrict__ mcp) {
  const int bh = blockIdx.x, b = bh / 6, h = bh % 6;
  const int t = threadIdx.x;
  __shared__ float Gs[1024];
  __shared__ float Acm[1024];
  __shared__ float Wp[192 * 32];
  __shared__ float nq[32], nk[32];
  #pragma unroll
  for (int i = 0; i < 3; ++i) {
    int idx = t + i * 512;
    int row = idx >> 3, c4 = (idx & 7) << 2;
    *(f32x4*)&Wp[row * 32 + c4] = *(const f32x4*)&wproj[(size_t)row * 192 + h * 32 + c4];
  }
  {
    const float* p = gp + (size_t)bh * 16 * 1024 + 2 * t;
    f32x2 s = {};
    #pragma unroll
    for (int ch = 0; ch < 16; ++ch) {
      f32x2 v = *(const f32x2*)&p[(size_t)ch * 1024];
      s[0] += v[0]; s[1] += v[1];
    }
    *(f32x2*)&Gs[2 * t] = s;
  }
  if (t < 64) {
    int c = t & 31, pk = t >> 5;
    const float* sp = ssq + (((size_t)b * 2 + pk) * 192 + h * 32 + c) * 16;
    f32x4 s4 = {};
    #pragma unroll
    for (int i = 0; i < 4; ++i) {
      f32x4 v = *(const f32x4*)&sp[4 * i];
      s4[0] += v[0]; s4[1] += v[1]; s4[2] += v[2]; s4[3] += v[3];
    }
    float nr = fmaxf(sqrtf(s4[0] + s4[1] + s4[2] + s4[3]), 1e-12f);
    if (pk == 0) nq[c] = nr; else nk[c] = nr;
  }
  __syncthreads();
  const float T = temp[h];
  {
    int c = (2 * t) >> 5;
    f32x2 v = *(const f32x2*)&Gs[2 * t];
    float inq = T / nq[c];
    v[0] = v[0] * inq / nk[(2 * t) & 31];
    v[1] = v[1] * inq / nk[(2 * t + 1) & 31];
    __syncthreads();
    *(f32x2*)&Gs[2 * t] = v;
  }
  __syncthreads();
  const float aw0 = aw[0], aw1 = aw[1], aw2 = aw[2], aw3 = aw[3];
  const int half = t >> 5, d = t & 31;
  #pragma unroll
  for (int it = 0; it < 2; ++it) {
    const int c = it * 16 + half;
    const float v = Gs[c * 32 + d];
    int cnt = 0;
    #pragma unroll
    for (int dd = 0; dd < 32; ++dd) cnt += (Gs[c * 32 + dd] >= v) ? 1 : 0;
    float c0 = v;
    float c1 = (cnt >= 16) ? v : -3.0e38f;
    float c2 = (cnt >= 21) ? v : -3.0e38f;
    float c3 = (cnt >= 24) ? v : -3.0e38f;
    float c4 = (cnt >= 25) ? v : -3.0e38f;
    #pragma unroll
    for (int off = 16; off; off >>= 1) {
      c0 = fmaxf(c0, __shfl_xor(c0, off));
      c1 = fmaxf(c1, __shfl_xor(c1, off));
      c2 = fmaxf(c2, __shfl_xor(c2, off));
      c3 = fmaxf(c3, __shfl_xor(c3, off));
      c4 = fmaxf(c4, __shfl_xor(c4, off));
    }
    const float m = c0;
    const float ex = expf(v - m);
    float z1 = (v >= c1) ? ex : 0.f;
    float z2 = (v >= c2) ? ex : 0.f;
    float z3 = (v >= c3) ? ex : 0.f;
    float z4 = (v >= c4) ? ex : 0.f;
    #pragma unroll
    for (int off = 16; off; off >>= 1) {
      z1 += __shfl_xor(z1, off);
      z2 += __shfl_xor(z2, off);
      z3 += __shfl_xor(z3, off);
      z4 += __shfl_xor(z4, off);
    }
    float a = 0.f;
    a += (v >= c1) ? aw0 * ex / z1 : 0.f;
    a += (v >= c2) ? aw1 * ex / z2 : 0.f;
    a += (v >= c3) ? aw2 * ex / z3 : 0.f;
    a += (v >= c4) ? aw3 * ex / z4 : 0.f;
    Acm[c * 32 + d] = a;
  }
  __syncthreads();
  #pragma unroll
  for (int i = 0; i < 12; ++i) {
    int idx = t + i * 512;
    int co = idx >> 5, dd = idx & 31;
    float s = 0.f;
    #pragma unroll
    for (int c = 0; c < 32; ++c) s += Wp[co * 32 + c] * Acm[c * 32 + dd];
    mcp[((size_t)b * 192 + co) * 192 + h * 32 + dd] = packsplit(s);
  }
}

// ---------------------------------------------------------------------------
extern "C" void kernel_launch(void* const* d_in, const int* in_sizes, int n_in,
                              void* d_out, int out_size, void* d_ws, size_t ws_size,
                              hipStream_t stream) {
  const float* x     = (const float*)d_in[0];
  const float* ref   = (const float*)d_in[1];
  const float* wqkv  = (const float*)d_in[2];
  const float* wdw   = (const float*)d_in[3];
  const float* wproj = (const float*)d_in[4];
  const float* temp  = (const float*)d_in[5];
  const float* aw    = (const float*)d_in[6];
  float* out = (float*)d_out;
  char* ws = (char*)d_ws;

  const size_t S = (size_t)4 * 192 * HW * 4;  // 50331648 bytes
  float* Ckv = (float*)(ws);                  // k+v conv-out (2S) [b][384][HW]
  float* Cq  = (float*)(ws + 2 * S);          // q conv-out (S)    [b][192][HW]
  u32*   qpk = (u32*)(ws + 3 * S);            // packed q (S); later vpk
  float* gp  = (float*)(ws + 4 * S);                        // 1572864 B
  float* ssq = (float*)(ws + 4 * S + 1572864);              // 98304 B
  u32*   wsp = (u32*)(ws + 4 * S + 1572864 + 98304);        // 442368 B
  u32*   mcp = (u32*)(ws + 4 * S + 1572864 + 98304 + 442368); // 589824 B
  u32*   kpk = (u32*)Cq;    // alias: Cq dead after k2(q)
  u32*   vpk = qpk;         // alias: qpk dead after k3

  // pre-split w_qkv (576x192)
  ksplit<<<dim3(432), 256, 0, stream>>>(wqkv, wsp, 576 * 192);
  // merged q+k+v conv1x1: y=0 -> q from x into Cq; y=1,2 -> k,v from ref into Ckv
  gemm6<0, 0><<<dim3(128, 3, 4), 512, 0, stream>>>(wsp, (const u32*)x, (const u32*)ref,
                                                   Cq, Ckv);
  // q dwconv -> qpk + ssq0
  k2_dw<1><<<dim3(16, 24, 4), 512, 0, stream>>>(Cq, 192, wdw, 0, qpk, ssq, 0);
  // k dwconv (Ckv rows 0..191) -> kpk (= Cq slot, dead) + ssq1
  k2_dw<1><<<dim3(16, 24, 4), 512, 0, stream>>>(Ckv, 384, wdw, 192, kpk, ssq, 1);
  // Gram partials
  k3_gram<<<dim3(16, 24), 256, 0, stream>>>(qpk, kpk, gp);
  // v dwconv (Ckv rows 192..383) -> vpk (= qpk slot, dead after k3)
  k2_dw<0><<<dim3(16, 24, 4), 512, 0, stream>>>(Ckv + (size_t)192 * HW, 384, wdw, 384,
                                                vpk, nullptr, 2);
  // combine + fold proj (writes packed mc)
  k4_comb<<<dim3(24), 512, 0, stream>>>(gp, ssq, temp, aw, wproj, mcp);
  // final batched GEMM (A batched packed, B packed)
  gemm6<1, 1><<<dim3(128, 1, 4), 512, 0, stream>>>(mcp, vpk, vpk, out, out);
}